// Round 1
// baseline (394.938 us; speedup 1.0000x reference)
//
#include <hip/hip_runtime.h>
#include <math.h>

#define DIMC 256
#define NH 8
#define NPIX 16384          // 128*128
#define BATCH 16
#define ATT_SCALE 0.17677669529663687f   // 1/sqrt(32)
#define LN_EPS 1e-5f

// ---------------------------------------------------------------------------
// K0: qk[b][h][c] = SCALE * sum_d q[b][h*32+d] * Wkv[h*32+d][c]
//     with q[b][i] = sum_c audio[b][c] * Wq[i][c]
// one block per b, 256 threads
// ---------------------------------------------------------------------------
__global__ __launch_bounds__(256) void k_qk(const float* __restrict__ audio,
                                            const float* __restrict__ Wq,
                                            const float* __restrict__ Wkv,
                                            float* __restrict__ qk) {
    int b = blockIdx.x;
    int t = threadIdx.x;
    __shared__ float aud[DIMC];
    __shared__ float qL[DIMC];
    aud[t] = audio[b * DIMC + t];
    __syncthreads();
    // q[i], i = t : row-per-thread read of Wq
    {
        const float* wr = Wq + (size_t)t * DIMC;
        float acc = 0.f;
        for (int c = 0; c < DIMC; c += 4) {
            float4 w = *(const float4*)(wr + c);
            acc = fmaf(w.x, aud[c], acc);
            acc = fmaf(w.y, aud[c + 1], acc);
            acc = fmaf(w.z, aud[c + 2], acc);
            acc = fmaf(w.w, aud[c + 3], acc);
        }
        qL[t] = acc;
    }
    __syncthreads();
    // qk[b][h][c], c = t ; coalesced row reads of Wkv
    {
        int c = t;
        float acc = 0.f;
        for (int i = 0; i < DIMC; ++i) {
            acc = fmaf(qL[i], Wkv[(size_t)i * DIMC + c], acc);
            if ((i & 31) == 31) {
                qk[((size_t)b * NH + (i >> 5)) * DIMC + c] = ATT_SCALE * acc;
                acc = 0.f;
            }
        }
    }
}

// ---------------------------------------------------------------------------
// K1: attn pass.  grid = B * (N/256) = 1024 blocks, 64 threads.
// thread owns 4 consecutive n (float4), loops over all 256 c (coalesced).
// a[b][h][n] = round(clip(attn,0,4))/4
// ---------------------------------------------------------------------------
__global__ __launch_bounds__(64) void k_attn(const float* __restrict__ fm,
                                             const float* __restrict__ qk,
                                             float* __restrict__ a) {
    int blk  = blockIdx.x;
    int b    = blk >> 6;        // 64 tiles per batch
    int tile = blk & 63;
    int t    = threadIdx.x;     // 0..63
    int n0   = tile * 256 + t * 4;

    __shared__ float qkL[DIMC][NH];   // [c][h], 8 KB
    for (int k = t; k < NH * DIMC; k += 64) {
        int h = k >> 8, c = k & 255;
        qkL[c][h] = qk[((size_t)b * NH + h) * DIMC + c];
    }
    __syncthreads();

    float att[NH][4];
#pragma unroll
    for (int h = 0; h < NH; ++h)
        att[h][0] = att[h][1] = att[h][2] = att[h][3] = 0.f;

    const float* fmb = fm + (size_t)b * DIMC * NPIX + n0;
#pragma unroll 4
    for (int c = 0; c < DIMC; ++c) {
        float4 v = *(const float4*)(fmb + (size_t)c * NPIX);
#pragma unroll
        for (int h = 0; h < NH; ++h) {
            float qv = qkL[c][h];
            att[h][0] = fmaf(v.x, qv, att[h][0]);
            att[h][1] = fmaf(v.y, qv, att[h][1]);
            att[h][2] = fmaf(v.z, qv, att[h][2]);
            att[h][3] = fmaf(v.w, qv, att[h][3]);
        }
    }

#pragma unroll
    for (int h = 0; h < NH; ++h) {
        float4 o;
        o.x = rintf(fminf(fmaxf(att[h][0], 0.f), 4.f)) * 0.25f;
        o.y = rintf(fminf(fmaxf(att[h][1], 0.f), 4.f)) * 0.25f;
        o.z = rintf(fminf(fmaxf(att[h][2], 0.f), 4.f)) * 0.25f;
        o.w = rintf(fminf(fmaxf(att[h][3], 0.f), 4.f)) * 0.25f;
        *(float4*)(a + ((size_t)b * NH + h) * NPIX + n0) = o;
    }
}

// ---------------------------------------------------------------------------
// K2: s partials.  grid = 1024 blocks (reversed order for L3 hits), 256 thr.
// thread owns channel c, accumulates s[h] over a 256-n slab (row-sequential
// reads, L1 line amortized).  a-loads are wave-uniform (scalarizable).
// ---------------------------------------------------------------------------
#define NSLAB 64   // slabs of 256 n
__global__ __launch_bounds__(256) void k_s(const float* __restrict__ fm,
                                           const float* __restrict__ a,
                                           float* __restrict__ s_part) {
    int rblk = (BATCH * NSLAB - 1) - blockIdx.x;   // reversed traversal
    int b    = rblk >> 6;
    int slab = rblk & (NSLAB - 1);
    int c    = threadIdx.x;
    int n0   = slab * 256;

    const float* fr = fm + ((size_t)b * DIMC + c) * NPIX + n0;
    const float* ab = a + (size_t)b * NH * NPIX + n0;

    float sc[NH];
#pragma unroll
    for (int h = 0; h < NH; ++h) sc[h] = 0.f;

#pragma unroll 2
    for (int j = 0; j < 256; j += 4) {
        float4 v = *(const float4*)(fr + j);
#pragma unroll
        for (int h = 0; h < NH; ++h) {
            float4 av = *(const float4*)(ab + (size_t)h * NPIX + j);
            float p = fmaf(v.x, av.x, fmaf(v.y, av.y, fmaf(v.z, av.z, v.w * av.w)));
            sc[h] += p;
        }
    }
#pragma unroll
    for (int h = 0; h < NH; ++h)
        s_part[(((size_t)b * NSLAB + slab) * NH + h) * DIMC + c] = sc[h];
}

// ---------------------------------------------------------------------------
// K3: reduce s partials -> s ; x = Wv*s ; p = Wp*x + bp ; LN ; spike -> scale
// one block per b, 256 threads
// ---------------------------------------------------------------------------
__global__ __launch_bounds__(256) void k_scale(const float* __restrict__ s_part,
                                               const float* __restrict__ Wkv,
                                               const float* __restrict__ Wp,
                                               const float* __restrict__ bp,
                                               const float* __restrict__ g,
                                               const float* __restrict__ beta,
                                               float* __restrict__ scale) {
    int b = blockIdx.x;
    int t = threadIdx.x;
    __shared__ float sL[NH][DIMC];
    __shared__ float xL[DIMC];
    __shared__ float red[8];
    __shared__ float mu_s, var_s;

    // fixed-order reduce over slabs
    for (int h = 0; h < NH; ++h) {
        float acc = 0.f;
        for (int sl = 0; sl < NSLAB; ++sl)
            acc += s_part[(((size_t)b * NSLAB + sl) * NH + h) * DIMC + t];
        sL[h][t] = acc;
    }
    __syncthreads();

    // x[i] = sum_c Wv[256+i][c] * s[i>>5][c]
    {
        const float* wr = Wkv + (size_t)(DIMC + t) * DIMC;
        const float* sr = sL[t >> 5];
        float acc = 0.f;
        for (int cc = 0; cc < DIMC; cc += 4) {
            float4 w = *(const float4*)(wr + cc);
            acc = fmaf(w.x, sr[cc], acc);
            acc = fmaf(w.y, sr[cc + 1], acc);
            acc = fmaf(w.z, sr[cc + 2], acc);
            acc = fmaf(w.w, sr[cc + 3], acc);
        }
        xL[t] = acc;
    }
    __syncthreads();

    // p[j] = sum_i Wp[j][i]*x[i] + bp[j]
    float p;
    {
        const float* wr = Wp + (size_t)t * DIMC;
        float acc = 0.f;
        for (int i = 0; i < DIMC; i += 4) {
            float4 w = *(const float4*)(wr + i);
            acc = fmaf(w.x, xL[i], acc);
            acc = fmaf(w.y, xL[i + 1], acc);
            acc = fmaf(w.z, xL[i + 2], acc);
            acc = fmaf(w.w, xL[i + 3], acc);
        }
        p = acc + bp[t];
    }

    // layernorm over 256 (two-pass: mean, then var)
    int lane = t & 63, wid = t >> 6;
    float r = p;
#pragma unroll
    for (int off = 32; off > 0; off >>= 1) r += __shfl_down(r, off);
    if (lane == 0) red[wid] = r;
    __syncthreads();
    if (t == 0) mu_s = (red[0] + red[1] + red[2] + red[3]) * (1.f / 256.f);
    __syncthreads();
    float mu = mu_s;
    float d = p - mu;
    float r2 = d * d;
#pragma unroll
    for (int off = 32; off > 0; off >>= 1) r2 += __shfl_down(r2, off);
    if (lane == 0) red[4 + wid] = r2;
    __syncthreads();
    if (t == 0) var_s = (red[4] + red[5] + red[6] + red[7]) * (1.f / 256.f);
    __syncthreads();

    float ln = d * (1.0f / sqrtf(var_s + LN_EPS)) * g[t] + beta[t];
    scale[b * DIMC + t] = rintf(fminf(fmaxf(ln, 0.f), 4.f)) * 0.25f;
}

// ---------------------------------------------------------------------------
// K4: out[b][c][n] = fm[b][c][n] * scale[b][c]   (grid-stride float4)
// ---------------------------------------------------------------------------
__global__ __launch_bounds__(256) void k_out(const float* __restrict__ fm,
                                             const float* __restrict__ scale,
                                             float* __restrict__ out) {
    const size_t total4 = (size_t)BATCH * DIMC * NPIX / 4;   // 16,777,216
    size_t stride = (size_t)gridDim.x * blockDim.x;
    size_t gid = (size_t)blockIdx.x * blockDim.x + threadIdx.x;
    for (size_t i = gid; i < total4; i += stride) {
        float4 v = *(const float4*)(fm + i * 4);
        float s = scale[i >> 12];                 // (b*256+c) = i / (N/4)
        float4 o;
        o.x = v.x * s; o.y = v.y * s; o.z = v.z * s; o.w = v.w * s;
        *(float4*)(out + i * 4) = o;
    }
}

// ---------------------------------------------------------------------------
extern "C" void kernel_launch(void* const* d_in, const int* in_sizes, int n_in,
                              void* d_out, int out_size, void* d_ws, size_t ws_size,
                              hipStream_t stream) {
    (void)in_sizes; (void)n_in; (void)out_size; (void)ws_size;
    const float* fm    = (const float*)d_in[0];
    const float* audio = (const float*)d_in[1];
    const float* Wq    = (const float*)d_in[2];
    const float* Wkv   = (const float*)d_in[3];
    const float* Wp    = (const float*)d_in[4];
    const float* bp    = (const float*)d_in[5];
    const float* g     = (const float*)d_in[6];
    const float* beta  = (const float*)d_in[7];
    float* out = (float*)d_out;

    char* ws = (char*)d_ws;
    float* qk     = (float*)(ws);                                  // 128 KB
    float* a      = (float*)(ws + (size_t)131072);                 // 8 MB
    float* s_part = (float*)(ws + (size_t)131072 + 8388608);       // 8 MB
    float* scale  = (float*)(ws + (size_t)131072 + 2 * 8388608);   // 16 KB

    hipLaunchKernelGGL(k_qk,    dim3(BATCH),        dim3(256), 0, stream, audio, Wq, Wkv, qk);
    hipLaunchKernelGGL(k_attn,  dim3(BATCH * 64),   dim3(64),  0, stream, fm, qk, a);
    hipLaunchKernelGGL(k_s,     dim3(BATCH * NSLAB),dim3(256), 0, stream, fm, a, s_part);
    hipLaunchKernelGGL(k_scale, dim3(BATCH),        dim3(256), 0, stream, s_part, Wkv, Wp, bp, g, beta, scale);
    hipLaunchKernelGGL(k_out,   dim3(2048),         dim3(256), 0, stream, fm, scale, out);
}